// Round 1
// baseline (16082.497 us; speedup 1.0000x reference)
//
#include <hip/hip_runtime.h>

// ViT forward (B=64, L=11, D=768, H=12, N=197, MLP=3072) on gfx950.
// Round 0: bf16-MFMA GEMM (m97-style 128x128 tile, global_load_lds) for all
// big matmuls; VALU attention; small kernels for LN / gconv / head.

typedef unsigned short u16;
typedef unsigned int u32;
typedef float f32x4 __attribute__((ext_vector_type(4)));
typedef __bf16 bf16x8 __attribute__((ext_vector_type(8)));

#define LAYERS 11
#define DIM 768
#define NTOK 197
#define NROWS 12608      // 64*197
#define MPAD 12672       // 99*128
#define QKVD 2304
#define MLPD 3072
#define NHEAD 12
#define NCLS 1000

static __device__ __forceinline__ float b2f(u16 v) {
  return __builtin_bit_cast(float, (u32)((u32)v << 16));
}
static __device__ __forceinline__ u16 f2b(float f) {
  u32 u = __builtin_bit_cast(u32, f);
  u += 0x7fffu + ((u >> 16) & 1u);
  return (u16)(u >> 16);
}
static __device__ __forceinline__ float lo2f(u32 u) { return __builtin_bit_cast(float, (u32)(u << 16)); }
static __device__ __forceinline__ float hi2f(u32 u) { return __builtin_bit_cast(float, (u32)(u & 0xffff0000u)); }

static __device__ __forceinline__ void gload16(const void* g, void* lds) {
  __builtin_amdgcn_global_load_lds((__attribute__((address_space(1))) void*)g,
                                   (__attribute__((address_space(3))) void*)lds, 16, 0, 0);
}

// ---------------- GEMM: C[M,N] = A[M,K](bf16) @ Bt[N,K](bf16)^T + epilogue ----
template <bool GELU>
__global__ __launch_bounds__(256) void gemm_bt(
    const u16* __restrict__ A, const u16* __restrict__ Bt,
    const float* __restrict__ bias, const float* resid,
    float* outf, u16* outb, int M, int N, int K)
{
  __shared__ __align__(16) u16 As[128 * 32];
  __shared__ __align__(16) u16 Bs[128 * 32];
  const int tid = threadIdx.x;
  const int lane = tid & 63;
  const int wv = tid >> 6;
  const int wr = (wv >> 1) * 64, wc = (wv & 1) * 64;
  const long am0 = (long)blockIdx.y * 128;
  const long bn0 = (long)blockIdx.x * 128;

  f32x4 acc[4][4];
#pragma unroll
  for (int i = 0; i < 4; ++i)
#pragma unroll
    for (int j = 0; j < 4; ++j) acc[i][j] = f32x4{0.f, 0.f, 0.f, 0.f};

  // staging: tile is 128 rows x 32 k (64B/row = 4 chunks of 16B); 512 chunks,
  // 2 per thread per matrix. LDS dest must be wave-uniform base (+lane*16 by HW).
  const int c0 = tid, c1 = tid + 256;
  const u16* a0 = A + (am0 + (c0 >> 2)) * K + (c0 & 3) * 8;
  const u16* a1 = A + (am0 + (c1 >> 2)) * K + (c1 & 3) * 8;
  const u16* b0 = Bt + (bn0 + (c0 >> 2)) * K + (c0 & 3) * 8;
  const u16* b1 = Bt + (bn0 + (c1 >> 2)) * K + (c1 & 3) * 8;
  char* As0 = (char*)As + (tid & ~63) * 16;
  char* As1 = (char*)As + (256 + (tid & ~63)) * 16;
  char* Bs0 = (char*)Bs + (tid & ~63) * 16;
  char* Bs1 = (char*)Bs + (256 + (tid & ~63)) * 16;

  const int fr = lane & 15;
  const int fko = (lane >> 4) * 8;

  for (int kk = 0; kk < K; kk += 32) {
    gload16(a0 + kk, As0);
    gload16(a1 + kk, As1);
    gload16(b0 + kk, Bs0);
    gload16(b1 + kk, Bs1);
    __syncthreads();
    uint4 af[4], bf[4];
#pragma unroll
    for (int i = 0; i < 4; ++i) {
      af[i] = *(const uint4*)(As + (wr + i * 16 + fr) * 32 + fko);
      bf[i] = *(const uint4*)(Bs + (wc + i * 16 + fr) * 32 + fko);
    }
#pragma unroll
    for (int mi = 0; mi < 4; ++mi)
#pragma unroll
      for (int ni = 0; ni < 4; ++ni)
        acc[mi][ni] = __builtin_amdgcn_mfma_f32_16x16x32_bf16(
            __builtin_bit_cast(bf16x8, af[mi]), __builtin_bit_cast(bf16x8, bf[ni]),
            acc[mi][ni], 0, 0, 0);
    __syncthreads();
  }

#pragma unroll
  for (int ni = 0; ni < 4; ++ni) {
    const long col = bn0 + wc + ni * 16 + fr;
    const float bv = bias ? bias[col] : 0.f;
#pragma unroll
    for (int mi = 0; mi < 4; ++mi) {
#pragma unroll
      for (int r = 0; r < 4; ++r) {
        const long row = am0 + wr + mi * 16 + (lane >> 4) * 4 + r;
        float v = acc[mi][ni][r] + bv;
        if (GELU) v = 0.5f * v * (1.f + erff(v * 0.70710678f));
        const long off = row * (long)N + col;
        if (resid) v += resid[off];
        if (outf) outf[off] = v;
        if (outb) outb[off] = f2b(v);
      }
    }
  }
}

// ---------------- weight transpose f32[R][C] -> bf16[C][R] -------------------
__global__ __launch_bounds__(256) void transpose_w(const float* __restrict__ in,
                                                   u16* __restrict__ out, int R, int C)
{
  __shared__ float t[32][33];
  const int tx = threadIdx.x & 31, ty = threadIdx.x >> 5;
  const int c0 = blockIdx.x * 32, r0 = blockIdx.y * 32;
#pragma unroll
  for (int j = 0; j < 4; ++j)
    t[ty + j * 8][tx] = in[(long)(r0 + ty + j * 8) * C + c0 + tx];
  __syncthreads();
#pragma unroll
  for (int j = 0; j < 4; ++j)
    out[(long)(c0 + ty + j * 8) * R + r0 + tx] = f2b(t[tx][ty + j * 8]);
}

__global__ void cvt_bf16_kernel(const float* __restrict__ in, u16* __restrict__ out, int n4) {
  const int i = blockIdx.x * 256 + threadIdx.x;
  if (i >= n4) return;
  const float4 v = ((const float4*)in)[i];
  ushort4 o;
  o.x = f2b(v.x); o.y = f2b(v.y); o.z = f2b(v.z); o.w = f2b(v.w);
  ((ushort4*)out)[i] = o;
}

// ---------------- patch embed: im2col + assemble -----------------------------
__global__ void im2col_kernel(const float* __restrict__ x, u16* __restrict__ A)
{
  const long i = (long)blockIdx.x * 256 + threadIdx.x;   // 12544*192 exact
  const int k4 = (int)(i % 192);
  const long row = i / 192;
  const int pw = (int)(row % 14);
  const long t = row / 14;
  const int ph = (int)(t % 14);
  const int b = (int)(t / 14);
  const int k = k4 * 4;
  const int c = k >> 8, rem = k & 255, p = rem >> 4, q = rem & 15;
  const float4 v = *(const float4*)(x + (((long)(b * 3 + c) * 224 + ph * 16 + p) * 224 + pw * 16 + q));
  ushort4 o;
  o.x = f2b(v.x); o.y = f2b(v.y); o.z = f2b(v.z); o.w = f2b(v.w);
  *(ushort4*)(A + row * DIM + k) = o;
}

__global__ void assemble_kernel(const float* __restrict__ tok, const float* __restrict__ cls,
                                const float* __restrict__ pos, float* __restrict__ xres)
{
  const long i = (long)blockIdx.x * 256 + threadIdx.x;   // 64*197*192 exact
  const int d4 = (int)(i % 192);
  const long bn = i / 192;
  const int n = (int)(bn % NTOK);
  const int b = (int)(bn / NTOK);
  const float4 p = *(const float4*)(pos + ((long)n * DIM + d4 * 4));
  float4 v;
  if (n == 0) v = *(const float4*)(cls + d4 * 4);
  else v = *(const float4*)(tok + ((long)(b * 196 + n - 1) * DIM + d4 * 4));
  float4 r;
  r.x = v.x + p.x; r.y = v.y + p.y; r.z = v.z + p.z; r.w = v.w + p.w;
  *(float4*)(xres + i * 4) = r;
}

// ---------------- LayerNorm: f32 row -> bf16 row (wave per row) --------------
__global__ __launch_bounds__(256) void ln_kernel(const float* __restrict__ x,
    const float* __restrict__ g, const float* __restrict__ bb, u16* __restrict__ out)
{
  const int lane = threadIdx.x & 63, w = threadIdx.x >> 6;
  const long row = (long)blockIdx.x * 4 + w;
  const float* xr = x + row * DIM;
  float v[12];
  float s = 0.f, sq = 0.f;
#pragma unroll
  for (int j = 0; j < 12; ++j) { v[j] = xr[lane + j * 64]; s += v[j]; sq += v[j] * v[j]; }
#pragma unroll
  for (int off = 32; off; off >>= 1) { s += __shfl_xor(s, off); sq += __shfl_xor(sq, off); }
  const float mu = s * (1.f / 768.f);
  const float rstd = rsqrtf(sq * (1.f / 768.f) - mu * mu + 1e-6f);
  u16* orow = out + row * DIM;
#pragma unroll
  for (int j = 0; j < 12; ++j)
    orow[lane + j * 64] = f2b((v[j] - mu) * rstd * g[lane + j * 64] + bb[lane + j * 64]);
}

// ---------------- attention: one block per (b,h) -----------------------------
__global__ __launch_bounds__(256) void attn_kernel(const u16* __restrict__ qkv, u16* __restrict__ o)
{
  __shared__ __align__(16) u16 Ks[NTOK * 66];
  __shared__ __align__(16) u16 Vs[NTOK * 66];
  __shared__ __align__(16) float qs[4][64];
  __shared__ __align__(16) float ps[4][200];
  const int tid = threadIdx.x, lane = tid & 63, w = tid >> 6;
  const int b = blockIdx.x / NHEAD, h = blockIdx.x % NHEAD;
  const long base = (long)b * NTOK * QKVD + h * 64;

  for (int idx = tid; idx < NTOK * 32; idx += 256) {
    const int j = idx >> 5, d2 = idx & 31;
    const long srow = base + (long)j * QKVD + d2 * 2;
    *(u32*)(Ks + j * 66 + d2 * 2) = *(const u32*)(qkv + srow + 768);
    *(u32*)(Vs + j * 66 + d2 * 2) = *(const u32*)(qkv + srow + 1536);
  }
  __syncthreads();

  for (int r = w; r < NTOK; r += 4) {
    const u16* qrow = qkv + base + (long)r * QKVD;
    qs[w][lane] = b2f(qrow[lane]);
    const u16* k0 = Ks + lane * 66;
    const u16* k1 = Ks + (lane + 64) * 66;
    const u16* k2 = Ks + (lane + 128) * 66;
    const bool has3 = lane < 5;
    const u16* k3 = Ks + (has3 ? (lane + 192) : 0) * 66;
    float s0 = 0.f, s1 = 0.f, s2 = 0.f, s3 = 0.f;
#pragma unroll 8
    for (int d2 = 0; d2 < 32; ++d2) {
      const float2 qp = *(const float2*)&qs[w][d2 * 2];
      const u32 p0 = *(const u32*)(k0 + d2 * 2);
      const u32 p1 = *(const u32*)(k1 + d2 * 2);
      const u32 p2 = *(const u32*)(k2 + d2 * 2);
      const u32 p3 = *(const u32*)(k3 + d2 * 2);
      s0 += qp.x * lo2f(p0) + qp.y * hi2f(p0);
      s1 += qp.x * lo2f(p1) + qp.y * hi2f(p1);
      s2 += qp.x * lo2f(p2) + qp.y * hi2f(p2);
      s3 += qp.x * lo2f(p3) + qp.y * hi2f(p3);
    }
    s0 *= 0.125f; s1 *= 0.125f; s2 *= 0.125f; s3 *= 0.125f;
    float mx = fmaxf(fmaxf(s0, s1), fmaxf(s2, has3 ? s3 : -1e30f));
#pragma unroll
    for (int off = 32; off; off >>= 1) mx = fmaxf(mx, __shfl_xor(mx, off));
    const float e0 = __expf(s0 - mx), e1 = __expf(s1 - mx), e2 = __expf(s2 - mx);
    const float e3 = has3 ? __expf(s3 - mx) : 0.f;
    float sum = e0 + e1 + e2 + e3;
#pragma unroll
    for (int off = 32; off; off >>= 1) sum += __shfl_xor(sum, off);
    ps[w][lane] = e0;
    ps[w][lane + 64] = e1;
    ps[w][lane + 128] = e2;
    if (has3) ps[w][lane + 192] = e3;
    const float inv = 1.f / sum;
    float oa = 0.f;
    const u16* vcol = Vs + lane;
#pragma unroll 7
    for (int j2 = 0; j2 < 98; ++j2) {
      const float2 pp = *(const float2*)&ps[w][j2 * 2];
      oa += pp.x * b2f(vcol[(j2 * 2) * 66]) + pp.y * b2f(vcol[(j2 * 2 + 1) * 66]);
    }
    oa += ps[w][196] * b2f(vcol[196 * 66]);
    o[((long)b * NTOK + r) * DIM + h * 64 + lane] = f2b(oa * inv);
  }
}

// ---------------- copy v of layer 0 ------------------------------------------
__global__ void v0copy_kernel(const u16* __restrict__ qkv, u16* __restrict__ v0) {
  const int i = blockIdx.x * 256 + threadIdx.x;   // NROWS*96 exact
  const int c8 = i % 96;
  const long row = i / 96;
  *(uint4*)(v0 + row * DIM + c8 * 8) = *(const uint4*)(qkv + row * QKVD + 1536 + c8 * 8);
}

// ---------------- block-diag gconv: per-head 64x64 ---------------------------
// MODE 1: uout = v0 - (W @ v + gb)          (v from qkv buffer, stride QKVD)
// MODE 2: hio += ALPHA * (W @ u + gb)       (u stride DIM)
template <int MODE>
__global__ __launch_bounds__(256) void bdg_kernel(const u16* __restrict__ vin,
    const u16* __restrict__ v0, const float* __restrict__ gw, const float* __restrict__ gb,
    u16* uout, u16* hio)
{
  __shared__ __align__(16) float gws[64 * 68];
  __shared__ __align__(16) float vb[4 * 68];
  const int tid = threadIdx.x, lane = tid & 63, w = tid >> 6;
  for (int idx = tid; idx < 4096; idx += 256) gws[(idx >> 6) * 68 + (idx & 63)] = gw[idx];
  __syncthreads();
  const long row = (long)blockIdx.x * 4 + w;
  const float gbl = gb[lane];
  const float4* gr = (const float4*)(gws + lane * 68);
  for (int h = 0; h < NHEAD; ++h) {
    float xv;
    if (MODE == 1) xv = b2f(vin[row * QKVD + 1536 + h * 64 + lane]);
    else xv = b2f(vin[row * DIM + h * 64 + lane]);
    vb[w * 68 + lane] = xv;
    float s = 0.f;
#pragma unroll
    for (int i4 = 0; i4 < 16; ++i4) {
      const float4 g4 = gr[i4];
      const float4 v4 = ((const float4*)(vb + w * 68))[i4];
      s += g4.x * v4.x + g4.y * v4.y + g4.z * v4.z + g4.w * v4.w;
    }
    s += gbl;
    const long off = row * DIM + h * 64 + lane;
    if (MODE == 1) uout[off] = f2b(b2f(v0[off]) - s);
    else hio[off] = f2b(b2f(hio[off]) + 0.6f * s);
  }
}

// ---------------- head: LN(cls) @ head_w (+ optional rev re-injection) -------
__global__ __launch_bounds__(256) void head_kernel(const float* xres,
    const float* __restrict__ ng, const float* __restrict__ nb,
    const float* __restrict__ hw, const float* __restrict__ hb,
    const float* __restrict__ rw, const float* __restrict__ rb,
    float* outx, float* outl, int final_mode)
{
  __shared__ float c[DIM];
  __shared__ float lg[NCLS];
  __shared__ float red[16];
  const int tid = threadIdx.x, lane = tid & 63, w = tid >> 6;
  const long brow = (long)blockIdx.x * NTOK * DIM;
  const float* xr = xres + brow;
  float s = 0.f, sq = 0.f;
  for (int d = tid; d < DIM; d += 256) { const float xv = xr[d]; s += xv; sq += xv * xv; }
#pragma unroll
  for (int off = 32; off; off >>= 1) { s += __shfl_xor(s, off); sq += __shfl_xor(sq, off); }
  if (lane == 0) { red[w] = s; red[8 + w] = sq; }
  __syncthreads();
  s = red[0] + red[1] + red[2] + red[3];
  sq = red[8] + red[9] + red[10] + red[11];
  const float mu = s * (1.f / 768.f);
  const float rstd = rsqrtf(sq * (1.f / 768.f) - mu * mu + 1e-6f);
  for (int d = tid; d < DIM; d += 256) c[d] = (xr[d] - mu) * rstd * ng[d] + nb[d];
  __syncthreads();
  for (int j = tid; j < NCLS; j += 256) {
    float a = hb[j];
#pragma unroll 4
    for (int d = 0; d < DIM; ++d) a += c[d] * hw[(long)d * NCLS + j];
    if (final_mode) outl[(long)blockIdx.x * NCLS + j] = a;
    else lg[j] = a;
  }
  if (!final_mode) {
    __syncthreads();
    for (int oo = tid; oo < DIM; oo += 256) {
      float a = rb[oo];
#pragma unroll 4
      for (int j = 0; j < NCLS; ++j) a += lg[j] * rw[(long)j * DIM + oo];
      outx[brow + oo] = a;
    }
  }
}

// =============================================================================
extern "C" void kernel_launch(void* const* d_in, const int* in_sizes, int n_in,
                              void* d_out, int out_size, void* d_ws, size_t ws_size,
                              hipStream_t stream)
{
  const float* x_img   = (const float*)d_in[0];
  const float* patch_w = (const float*)d_in[1];
  const float* patch_b = (const float*)d_in[2];
  const float* cls_tok = (const float*)d_in[3];
  const float* pos_emb = (const float*)d_in[4];
  const float* qkv_w   = (const float*)d_in[5];
  const float* qkv_b   = (const float*)d_in[6];
  const float* proj_w  = (const float*)d_in[7];
  const float* proj_b  = (const float*)d_in[8];
  const float* gconv_w = (const float*)d_in[9];
  const float* gconv_b = (const float*)d_in[10];
  const float* n1_g    = (const float*)d_in[11];
  const float* n1_b    = (const float*)d_in[12];
  const float* n2_g    = (const float*)d_in[13];
  const float* n2_b    = (const float*)d_in[14];
  const float* fc1_w   = (const float*)d_in[15];
  const float* fc1_b   = (const float*)d_in[16];
  const float* fc2_w   = (const float*)d_in[17];
  const float* fc2_b   = (const float*)d_in[18];
  const float* norm_g  = (const float*)d_in[19];
  const float* norm_b  = (const float*)d_in[20];
  const float* head_w  = (const float*)d_in[21];
  const float* head_b  = (const float*)d_in[22];
  const float* rev_w   = (const float*)d_in[23];
  const float* rev_b   = (const float*)d_in[24];

  char* ws = (char*)d_ws;
  size_t off = 0;
  auto alloc = [&](size_t bytes) -> void* {
    void* p = ws + off;
    off += (bytes + 255) & ~(size_t)255;
    return p;
  };
  float* xres = (float*)alloc((size_t)MPAD * DIM * 4);
  u16* hbuf   = (u16*)alloc((size_t)MPAD * DIM * 2);
  u16* big    = (u16*)alloc((size_t)MPAD * MLPD * 2);     // qkv (2304) or mlp (3072) or tok f32
  u16* v0buf  = (u16*)alloc((size_t)NROWS * DIM * 2);
  u16* ubuf   = (u16*)alloc((size_t)NROWS * DIM * 2);
  u16* wq     = (u16*)alloc((size_t)QKVD * DIM * 2);
  u16* wp     = (u16*)alloc((size_t)DIM * DIM * 2);
  u16* wf1    = (u16*)alloc((size_t)MLPD * DIM * 2);
  u16* wf2    = (u16*)alloc((size_t)DIM * MLPD * 2);
  u16* wpatch = (u16*)alloc((size_t)DIM * DIM * 2);

  // ---- patch embed ----
  cvt_bf16_kernel<<<576, 256, 0, stream>>>(patch_w, wpatch, 147456);
  im2col_kernel<<<9408, 256, 0, stream>>>(x_img, hbuf);
  gemm_bt<false><<<dim3(6, 98), 256, 0, stream>>>(hbuf, wpatch, patch_b, nullptr,
                                                  (float*)big, nullptr, 12544, DIM, DIM);
  assemble_kernel<<<9456, 256, 0, stream>>>((const float*)big, cls_tok, pos_emb, xres);

  for (int i = 0; i < LAYERS; ++i) {
    transpose_w<<<dim3(72, 24), 256, 0, stream>>>(qkv_w + (size_t)i * DIM * QKVD, wq, DIM, QKVD);
    transpose_w<<<dim3(24, 24), 256, 0, stream>>>(proj_w + (size_t)i * DIM * DIM, wp, DIM, DIM);
    transpose_w<<<dim3(96, 24), 256, 0, stream>>>(fc1_w + (size_t)i * DIM * MLPD, wf1, DIM, MLPD);
    transpose_w<<<dim3(24, 96), 256, 0, stream>>>(fc2_w + (size_t)i * MLPD * DIM, wf2, MLPD, DIM);

    ln_kernel<<<3152, 256, 0, stream>>>(xres, n1_g + i * DIM, n1_b + i * DIM, hbuf);
    gemm_bt<false><<<dim3(18, 99), 256, 0, stream>>>(hbuf, wq, qkv_b + i * QKVD, nullptr,
                                                     nullptr, big, MPAD, QKVD, DIM);
    if (i == 0) v0copy_kernel<<<4728, 256, 0, stream>>>(big, v0buf);
    attn_kernel<<<768, 256, 0, stream>>>(big, hbuf);
    if (i > 0) {
      bdg_kernel<1><<<3152, 256, 0, stream>>>(big, v0buf, gconv_w + i * 4096,
                                              gconv_b + i * 64, ubuf, nullptr);
      bdg_kernel<2><<<3152, 256, 0, stream>>>(ubuf, nullptr, gconv_w + i * 4096,
                                              gconv_b + i * 64, nullptr, hbuf);
    }
    gemm_bt<false><<<dim3(6, 99), 256, 0, stream>>>(hbuf, wp, proj_b + i * DIM, xres,
                                                    xres, nullptr, MPAD, DIM, DIM);
    ln_kernel<<<3152, 256, 0, stream>>>(xres, n2_g + i * DIM, n2_b + i * DIM, hbuf);
    gemm_bt<true><<<dim3(24, 99), 256, 0, stream>>>(hbuf, wf1, fc1_b + i * MLPD, nullptr,
                                                    nullptr, big, MPAD, MLPD, DIM);
    gemm_bt<false><<<dim3(6, 99), 256, 0, stream>>>(big, wf2, fc2_b + i * DIM, xres,
                                                    xres, nullptr, MPAD, DIM, MLPD);
    if (i >= 1)
      head_kernel<<<64, 256, 0, stream>>>(xres, norm_g, norm_b, head_w, head_b,
                                          rev_w, rev_b, xres, nullptr, 0);
  }
  head_kernel<<<64, 256, 0, stream>>>(xres, norm_g, norm_b, head_w, head_b,
                                      rev_w, rev_b, nullptr, (float*)d_out, 1);
}